// Round 1
// baseline (1467.626 us; speedup 1.0000x reference)
//
#include <hip/hip_runtime.h>
#include <hip/hip_bf16.h>

// Problem constants
#define NTOK   8192      // B*T
#define DDIM   1024
#define NHEADS 4
#define KDIM   256
#define HALF   128
#define NKEYS  1024
#define KNN    32
#define VDIM   32
#define CHUNK  1024      // tokens per scores chunk

// ---------------------------------------------------------------------------
// K1/K2: fp32 tiled GEMM, 64x64 tile, BK=16, 256 threads, 4x4 micro-tile.
// BT=false: C = A(MxK) * B(KxN)  (B row-major K x N)
// BT=true : C = A(MxK) * B^T     (B row-major N x K)
// blockIdx.z strides A/B/C by sAz/sBz/sCz (floats) for batched use.
// ---------------------------------------------------------------------------
template <bool BT>
__global__ __launch_bounds__(256) void gemm64(const float* __restrict__ A,
                                              const float* __restrict__ B,
                                              const float* __restrict__ bias,
                                              float* __restrict__ C,
                                              int K, int lda, int ldb, int ldc,
                                              long sAz, long sBz, long sCz) {
  __shared__ float As[16][68];   // [k][m]
  __shared__ float Bs[16][68];   // [k][n]
  A += (size_t)blockIdx.z * sAz;
  B += (size_t)blockIdx.z * sBz;
  C += (size_t)blockIdx.z * sCz;

  const int tid = threadIdx.x;
  const int tx = tid & 15, ty = tid >> 4;
  const size_t bm = (size_t)blockIdx.x * 64;
  const size_t bn = (size_t)blockIdx.y * 64;

  float acc[4][4];
#pragma unroll
  for (int i = 0; i < 4; i++)
#pragma unroll
    for (int j = 0; j < 4; j++) acc[i][j] = 0.f;

  for (int k0 = 0; k0 < K; k0 += 16) {
    // A tile: 64(m) x 16(k), 4 floats per thread (float4 along k), transpose into As[k][m]
    {
      const int r = tid >> 2, c4 = (tid & 3) << 2;
      const float4 av = *reinterpret_cast<const float4*>(&A[(bm + r) * (size_t)lda + (k0 + c4)]);
      As[c4 + 0][r] = av.x; As[c4 + 1][r] = av.y; As[c4 + 2][r] = av.z; As[c4 + 3][r] = av.w;
    }
    if (BT) {
      // B tile from N x K storage: 64(n) x 16(k) -> Bs[k][n]
      const int r = tid >> 2, c4 = (tid & 3) << 2;
      const float4 bv = *reinterpret_cast<const float4*>(&B[(bn + r) * (size_t)ldb + (k0 + c4)]);
      Bs[c4 + 0][r] = bv.x; Bs[c4 + 1][r] = bv.y; Bs[c4 + 2][r] = bv.z; Bs[c4 + 3][r] = bv.w;
    } else {
      // B tile from K x N storage: 16(k) x 64(n) -> Bs[k][n]
      const int r = tid >> 4, c4 = (tid & 15) << 2;
      const float4 bv = *reinterpret_cast<const float4*>(&B[(size_t)(k0 + r) * ldb + bn + c4]);
      *reinterpret_cast<float4*>(&Bs[r][c4]) = bv;
    }
    __syncthreads();
#pragma unroll
    for (int kk = 0; kk < 16; kk++) {
      const float4 a4 = *reinterpret_cast<const float4*>(&As[kk][ty << 2]);
      const float4 b4 = *reinterpret_cast<const float4*>(&Bs[kk][tx << 2]);
      const float aa[4] = {a4.x, a4.y, a4.z, a4.w};
      const float bb[4] = {b4.x, b4.y, b4.z, b4.w};
#pragma unroll
      for (int i = 0; i < 4; i++)
#pragma unroll
        for (int j = 0; j < 4; j++) acc[i][j] = fmaf(aa[i], bb[j], acc[i][j]);
    }
    __syncthreads();
  }

  const int col0 = (int)bn + (tx << 2);
  float4 bv4 = make_float4(0.f, 0.f, 0.f, 0.f);
  if (bias) bv4 = *reinterpret_cast<const float4*>(&bias[col0]);
#pragma unroll
  for (int i = 0; i < 4; i++) {
    const size_t row = bm + (ty << 2) + i;
    float4 ov;
    ov.x = acc[i][0] + bv4.x;
    ov.y = acc[i][1] + bv4.y;
    ov.z = acc[i][2] + bv4.z;
    ov.w = acc[i][3] + bv4.w;
    *reinterpret_cast<float4*>(&C[row * (size_t)ldc + col0]) = ov;
  }
}

// ---------------------------------------------------------------------------
// K3: exact top-32 of 1024 scores per (n,h,c) group. One wave per group.
// Outputs values sorted descending + their indices.
// ---------------------------------------------------------------------------
__global__ __launch_bounds__(256) void topk_subkeys(const float* __restrict__ sc,
                                                    float* __restrict__ sv,
                                                    int* __restrict__ si,
                                                    int group_base) {
  const int lane = threadIdx.x & 63;
  const int gl = blockIdx.x * 4 + (threadIdx.x >> 6);
  const float* s = sc + (size_t)gl * 1024;

  float v[16];
#pragma unroll
  for (int j = 0; j < 16; j++) v[j] = s[lane + 64 * j];

  unsigned removed = 0u;
  const size_t gg = (size_t)(group_base + gl);

#pragma unroll 1
  for (int it = 0; it < KNN; it++) {
    float best = -3e38f;
    int bj = 0;
#pragma unroll
    for (int j = 0; j < 16; j++) {
      const bool ok = (((removed >> j) & 1u) == 0u) && (v[j] > best);
      best = ok ? v[j] : best;
      bj = ok ? j : bj;
    }
    float wv = best;
    int wl = lane, wj = bj;
#pragma unroll
    for (int off = 32; off; off >>= 1) {
      const float ov = __shfl_xor(wv, off);
      const int ol = __shfl_xor(wl, off);
      const int oj = __shfl_xor(wj, off);
      const bool take = (ov > wv) || (ov == wv && ol < wl);
      wv = take ? ov : wv;
      wl = take ? ol : wl;
      wj = take ? oj : wj;
    }
    if (lane == wl) removed |= (1u << wj);
    if (lane == 0) {
      sv[gg * KNN + it] = wv;
      si[gg * KNN + it] = wl + 64 * wj;
    }
  }
}

// ---------------------------------------------------------------------------
// K4: per token (block), per head (wave): top-32 of the 32x32 combo sums,
// online softmax, gather value rows, weighted sum; then head reduction.
// ---------------------------------------------------------------------------
__global__ __launch_bounds__(256) void combine_topk(const float* __restrict__ sv,
                                                    const int* __restrict__ si,
                                                    const float* __restrict__ values,
                                                    float* __restrict__ y) {
  const int n = blockIdx.x;
  const int w = threadIdx.x >> 6;   // head
  const int lane = threadIdx.x & 63;

  __shared__ float s1v[4][32], s2v[4][32];
  __shared__ int s1i[4][32], s2i[4][32];
  __shared__ float yh[4][32];

  const size_t g1 = ((size_t)(n * 8 + w * 2)) * KNN;       // (n,h,c=0)
  const size_t g2 = g1 + KNN;                              // (n,h,c=1)
  if (lane < 32) {
    s1v[w][lane] = sv[g1 + lane];
    s1i[w][lane] = si[g1 + lane];
  } else {
    s2v[w][lane - 32] = sv[g2 + lane - 32];
    s2i[w][lane - 32] = si[g2 + lane - 32];
  }

  float v[16];
#pragma unroll
  for (int t = 0; t < 16; t++) {
    const int c = lane + 64 * t;            // 0..1023, i=c>>5, j=c&31
    v[t] = s1v[w][c >> 5] + s2v[w][c & 31];
  }

  unsigned removed = 0u;
  float m = 0.f, es = 0.f, acc = 0.f;

#pragma unroll 1
  for (int it = 0; it < KNN; it++) {
    float best = -3e38f;
    int bj = 0;
#pragma unroll
    for (int j = 0; j < 16; j++) {
      const bool ok = (((removed >> j) & 1u) == 0u) && (v[j] > best);
      best = ok ? v[j] : best;
      bj = ok ? j : bj;
    }
    float wv = best;
    int wl = lane, wj = bj;
#pragma unroll
    for (int off = 32; off; off >>= 1) {
      const float ov = __shfl_xor(wv, off);
      const int ol = __shfl_xor(wl, off);
      const int oj = __shfl_xor(wj, off);
      const bool take = (ov > wv) || (ov == wv && ol < wl);
      wv = take ? ov : wv;
      wl = take ? ol : wl;
      wj = take ? oj : wj;
    }
    if (lane == wl) removed |= (1u << wj);

    const int c = wl + 64 * wj;
    if (it == 0) m = wv;
    const float e = __expf(wv - m);
    es += e;
    const int idx = s1i[w][c >> 5] * NKEYS + s2i[w][c & 31];
    if (lane < 32) acc += e * values[(size_t)idx * VDIM + lane];
  }

  if (lane < 32) yh[w][lane] = acc / es;
  __syncthreads();
  if (w == 0 && lane < 32) {
    y[(size_t)n * VDIM + lane] = yh[0][lane] + yh[1][lane] + yh[2][lane] + yh[3][lane];
  }
}

// ---------------------------------------------------------------------------
// K5: out = x + y @ W_r + b_r.  8 tokens per block; W_r columns reused in regs.
// ---------------------------------------------------------------------------
__global__ __launch_bounds__(256) void out_proj(const float* __restrict__ x,
                                                const float* __restrict__ yv,
                                                const float* __restrict__ Wr,
                                                const float* __restrict__ br,
                                                float* __restrict__ out) {
  const int nb = blockIdx.x * 8;
  const int t = threadIdx.x;
  __shared__ float ys[8][VDIM];
  ys[t >> 5][t & 31] = yv[(size_t)nb * VDIM + t];
  __syncthreads();

#pragma unroll
  for (int rep = 0; rep < 4; rep++) {
    const int d = t + rep * 256;
    float wcol[VDIM];
#pragma unroll
    for (int vv = 0; vv < VDIM; vv++) wcol[vv] = Wr[vv * DDIM + d];
    const float bb = br[d];
#pragma unroll 1
    for (int tok = 0; tok < 8; tok++) {
      float a = bb;
#pragma unroll
      for (int vv = 0; vv < VDIM; vv++) a = fmaf(ys[tok][vv], wcol[vv], a);
      const size_t o = (size_t)(nb + tok) * DDIM + d;
      out[o] = x[o] + a;
    }
  }
}

// ---------------------------------------------------------------------------
extern "C" void kernel_launch(void* const* d_in, const int* in_sizes, int n_in,
                              void* d_out, int out_size, void* d_ws, size_t ws_size,
                              hipStream_t stream) {
  const float* x      = (const float*)d_in[0];
  const float* W_q    = (const float*)d_in[1];
  const float* b_q    = (const float*)d_in[2];
  const float* keys   = (const float*)d_in[3];
  const float* values = (const float*)d_in[4];
  const float* W_r    = (const float*)d_in[5];
  const float* b_r    = (const float*)d_in[6];
  float* out = (float*)d_out;

  // Workspace layout (floats): q | sv | si | y | scores_chunk
  float* q  = (float*)d_ws;
  float* sv = q + (size_t)NTOK * DDIM;                     // 65536*32
  int*   si = (int*)(sv + (size_t)NTOK * NHEADS * 2 * KNN);
  float* y  = (float*)(si + (size_t)NTOK * NHEADS * 2 * KNN);
  float* sc = y + (size_t)NTOK * VDIM;                     // CHUNK*8*1024

  // K1: q = x @ W_q + b_q   (8192x1024x1024)
  gemm64<false><<<dim3(NTOK / 64, DDIM / 64, 1), 256, 0, stream>>>(
      x, W_q, b_q, q, DDIM, DDIM, DDIM, DDIM, 0, 0, 0);

  // K2+K3 per chunk of tokens
  for (int ch = 0; ch < NTOK / CHUNK; ch++) {
    // scores[n_local][hc][key] = q_slice . keys^T ; z = hc in 0..7
    gemm64<true><<<dim3(CHUNK / 64, NKEYS / 64, NHEADS * 2), 256, 0, stream>>>(
        q + (size_t)ch * CHUNK * DDIM, keys, nullptr, sc,
        HALF, DDIM, HALF, NHEADS * 2 * NKEYS,
        /*sAz=*/HALF, /*sBz=*/(long)NKEYS * HALF, /*sCz=*/NKEYS);
    topk_subkeys<<<CHUNK * NHEADS * 2 / 4, 256, 0, stream>>>(sc, sv, si, ch * CHUNK * NHEADS * 2);
  }

  // K4: combine halves, top-32, softmax, value gather, head sum
  combine_topk<<<NTOK, 256, 0, stream>>>(sv, si, values, y);

  // K5: out = x + y @ W_r + b_r
  out_proj<<<NTOK / 8, 256, 0, stream>>>(x, y, W_r, b_r, out);
}

// Round 6
// 886.542 us; speedup vs baseline: 1.6554x; 1.6554x over previous
//
#include <hip/hip_runtime.h>
#include <hip/hip_bf16.h>

// Problem constants
#define NTOK   8192      // B*T
#define DDIM   1024
#define NHEADS 4
#define KDIM   256
#define HALF   128
#define NKEYS  1024
#define KNN    32
#define VDIM   32
#define CHUNK  1024      // tokens per scores chunk

typedef __attribute__((ext_vector_type(8))) short bf16x8;
typedef __attribute__((ext_vector_type(4))) float f32x4;

__device__ __forceinline__ unsigned short f2bf(float f) {
  __hip_bfloat16 h = __float2bfloat16(f);
  return *reinterpret_cast<unsigned short*>(&h);
}

// ---------------------------------------------------------------------------
// Convert fp32 -> bf16 (flat, n multiple of 4)
// ---------------------------------------------------------------------------
__global__ __launch_bounds__(256) void cvt_bf16(const float* __restrict__ in,
                                                unsigned short* __restrict__ out, int n4) {
  int i = blockIdx.x * 256 + threadIdx.x;
  if (i >= n4) return;
  const float4 v = reinterpret_cast<const float4*>(in)[i];
  ushort4 o;
  o.x = f2bf(v.x); o.y = f2bf(v.y); o.z = f2bf(v.z); o.w = f2bf(v.w);
  reinterpret_cast<ushort4*>(out)[i] = o;
}

// ---------------------------------------------------------------------------
// W_q (K x N = 1024x1024) -> W_qT bf16 (N x K)
// ---------------------------------------------------------------------------
__global__ __launch_bounds__(256) void transpose_cvt(const float* __restrict__ W,
                                                     unsigned short* __restrict__ Wt) {
  __shared__ float t[64][65];
  const int bi = blockIdx.y, bj = blockIdx.x;
  const int tid = threadIdx.x;
  const int col = tid & 63;
#pragma unroll
  for (int p = 0; p < 16; p++) {
    const int row = p * 4 + (tid >> 6);
    t[row][col] = W[(size_t)(bi * 64 + row) * DDIM + bj * 64 + col];
  }
  __syncthreads();
#pragma unroll
  for (int p = 0; p < 16; p++) {
    const int row = p * 4 + (tid >> 6);
    Wt[(size_t)(bj * 64 + row) * DDIM + bi * 64 + col] = f2bf(t[col][row]);
  }
}

// ---------------------------------------------------------------------------
// bf16 MFMA GEMM: C[M,N] = A[M,K] * B[N,K]^T (+bias). 128x128 tile, BK=32,
// 256 threads = 4 waves (2x2 of 64x64), mfma_f32_16x16x32_bf16.
// LDS rows padded to 40 elems (80 B = 5*16 B): 16B-aligned b128 ops AND
// bank-start = row*20 mod 32 -> balanced across all 32 banks.
// OBF: write bf16 output, else fp32. blockIdx.z batch with strides (elems).
// ---------------------------------------------------------------------------
template <bool OBF, bool BIAS>
__global__ __launch_bounds__(256) void gemm_mfma(const unsigned short* __restrict__ A,
                                                 const unsigned short* __restrict__ B,
                                                 const float* __restrict__ bias,
                                                 void* __restrict__ Cv,
                                                 int K, int lda, int ldb, int ldc,
                                                 long sAz, long sBz, long sCz) {
  __shared__ unsigned short As[128][40];
  __shared__ unsigned short Bs[128][40];
  A += (size_t)blockIdx.z * sAz;
  B += (size_t)blockIdx.z * sBz;
  const int tid = threadIdx.x, lane = tid & 63, wv = tid >> 6;
  const int wr = wv >> 1, wc = wv & 1;
  const size_t bm = (size_t)blockIdx.x * 128;
  const size_t bn = (size_t)blockIdx.y * 128;

  // staging: 512 chunks of 8 bf16; this thread owns chunks tid and tid+256
  const int c0 = tid, c1 = tid + 256;
  const int r0 = c0 >> 2, k0c = (c0 & 3) * 8;
  const int r1 = c1 >> 2, k1c = (c1 & 3) * 8;
  const unsigned short* Ap0 = A + (bm + r0) * (size_t)lda + k0c;
  const unsigned short* Ap1 = A + (bm + r1) * (size_t)lda + k1c;
  const unsigned short* Bp0 = B + (bn + r0) * (size_t)ldb + k0c;
  const unsigned short* Bp1 = B + (bn + r1) * (size_t)ldb + k1c;

  f32x4 acc[4][4];
#pragma unroll
  for (int m = 0; m < 4; m++)
#pragma unroll
    for (int n = 0; n < 4; n++) acc[m][n] = (f32x4){0.f, 0.f, 0.f, 0.f};

  const int fr = lane & 15;     // fragment row/col
  const int fk = lane >> 4;     // k-quarter (8 elems each)

  for (int kt = 0; kt < K; kt += 32) {
    const bf16x8 ra0 = *reinterpret_cast<const bf16x8*>(Ap0 + kt);
    const bf16x8 ra1 = *reinterpret_cast<const bf16x8*>(Ap1 + kt);
    const bf16x8 rb0 = *reinterpret_cast<const bf16x8*>(Bp0 + kt);
    const bf16x8 rb1 = *reinterpret_cast<const bf16x8*>(Bp1 + kt);
    __syncthreads();   // previous iteration's fragment reads done
    *reinterpret_cast<bf16x8*>(&As[r0][k0c]) = ra0;
    *reinterpret_cast<bf16x8*>(&As[r1][k1c]) = ra1;
    *reinterpret_cast<bf16x8*>(&Bs[r0][k0c]) = rb0;
    *reinterpret_cast<bf16x8*>(&Bs[r1][k1c]) = rb1;
    __syncthreads();   // tile ready

    bf16x8 af[4], bfv[4];
#pragma unroll
    for (int m = 0; m < 4; m++)
      af[m] = *reinterpret_cast<const bf16x8*>(&As[wr * 64 + m * 16 + fr][fk * 8]);
#pragma unroll
    for (int n = 0; n < 4; n++)
      bfv[n] = *reinterpret_cast<const bf16x8*>(&Bs[wc * 64 + n * 16 + fr][fk * 8]);
#pragma unroll
    for (int m = 0; m < 4; m++)
#pragma unroll
      for (int n = 0; n < 4; n++)
        acc[m][n] = __builtin_amdgcn_mfma_f32_16x16x32_bf16(af[m], bfv[n], acc[m][n], 0, 0, 0);
  }

  // epilogue: C/D layout col = lane&15, row = (lane>>4)*4 + q
#pragma unroll
  for (int n = 0; n < 4; n++) {
    const size_t col = bn + wc * 64 + n * 16 + fr;
    const float bv = BIAS ? bias[col] : 0.f;
#pragma unroll
    for (int m = 0; m < 4; m++) {
#pragma unroll
      for (int q = 0; q < 4; q++) {
        const size_t row = bm + wr * 64 + m * 16 + fk * 4 + q;
        const float val = acc[m][n][q] + bv;
        const size_t o = ((size_t)blockIdx.z * (size_t)sCz) + row * (size_t)ldc + col;
        if (OBF) ((unsigned short*)Cv)[o] = f2bf(val);
        else     ((float*)Cv)[o] = val;
      }
    }
  }
}

// ---------------------------------------------------------------------------
// K3: exact top-32 of 1024 scores per (n,h,c) group. One wave per group.
// Outputs values sorted descending + their indices.
// ---------------------------------------------------------------------------
__global__ __launch_bounds__(256) void topk_subkeys(const float* __restrict__ sc,
                                                    float* __restrict__ sv,
                                                    int* __restrict__ si,
                                                    int group_base) {
  const int lane = threadIdx.x & 63;
  const int gl = blockIdx.x * 4 + (threadIdx.x >> 6);
  const float* s = sc + (size_t)gl * 1024;

  float v[16];
#pragma unroll
  for (int j = 0; j < 16; j++) v[j] = s[lane + 64 * j];

  unsigned removed = 0u;
  const size_t gg = (size_t)(group_base + gl);

#pragma unroll 1
  for (int it = 0; it < KNN; it++) {
    float best = -3e38f;
    int bj = 0;
#pragma unroll
    for (int j = 0; j < 16; j++) {
      const bool ok = (((removed >> j) & 1u) == 0u) && (v[j] > best);
      best = ok ? v[j] : best;
      bj = ok ? j : bj;
    }
    float wv = best;
    int wl = lane, wj = bj;
#pragma unroll
    for (int off = 32; off; off >>= 1) {
      const float ov = __shfl_xor(wv, off);
      const int ol = __shfl_xor(wl, off);
      const int oj = __shfl_xor(wj, off);
      const bool take = (ov > wv) || (ov == wv && ol < wl);
      wv = take ? ov : wv;
      wl = take ? ol : wl;
      wj = take ? oj : wj;
    }
    if (lane == wl) removed |= (1u << wj);
    if (lane == 0) {
      sv[gg * KNN + it] = wv;
      si[gg * KNN + it] = wl + 64 * wj;
    }
  }
}

// ---------------------------------------------------------------------------
// K4 v2: staircase candidates (119 of 1024) + bitonic sort of 128 across
// 64 lanes x 2 regs; softmax + value gather from sorted lanes.
// An element (i,j) of s1+s2 (both sorted desc) can be in the top-32 only if
// (i+1)*(j+1) <= 32: exactly 119 candidates.
// ---------------------------------------------------------------------------
__device__ const short CAND[128] = {
  // i=0: j=0..31
  0,1,2,3,4,5,6,7,8,9,10,11,12,13,14,15,16,17,18,19,20,21,22,23,24,25,26,27,28,29,30,31,
  // i=1: j=0..15
  32,33,34,35,36,37,38,39,40,41,42,43,44,45,46,47,
  // i=2: j=0..9
  64,65,66,67,68,69,70,71,72,73,
  // i=3: j=0..7
  96,97,98,99,100,101,102,103,
  // i=4: j=0..5
  128,129,130,131,132,133,
  // i=5: j=0..4
  160,161,162,163,164,
  // i=6: j=0..3
  192,193,194,195,
  // i=7: j=0..3
  224,225,226,227,
  // i=8,9: j=0..2
  256,257,258, 288,289,290,
  // i=10..15: j=0..1
  320,321, 352,353, 384,385, 416,417, 448,449, 480,481,
  // i=16..31: j=0
  512,544,576,608,640,672,704,736,768,800,832,864,896,928,960,992,
  // pad
  -1,-1,-1,-1,-1,-1,-1,-1,-1
};

__global__ __launch_bounds__(256) void combine_topk2(const float* __restrict__ sv,
                                                     const int* __restrict__ si,
                                                     const float* __restrict__ values,
                                                     float* __restrict__ y) {
  const int n = blockIdx.x;
  const int w = threadIdx.x >> 6;   // head
  const int lane = threadIdx.x & 63;

  __shared__ float s1v[4][32], s2v[4][32];
  __shared__ int s1i[4][32], s2i[4][32];
  __shared__ float yh[4][32];

  const size_t g1 = ((size_t)(n * 8 + w * 2)) * KNN;   // (n,h,c=0)
  const size_t g2 = g1 + KNN;                          // (n,h,c=1)
  if (lane < 32) {
    s1v[w][lane] = sv[g1 + lane];
    s1i[w][lane] = si[g1 + lane];
  } else {
    s2v[w][lane - 32] = sv[g2 + lane - 32];
    s2i[w][lane - 32] = si[g2 + lane - 32];
  }

  // candidate values: virtual index e = reg*64 + lane
  int id0 = CAND[lane], id1 = CAND[64 + lane];
  float v0 = (id0 < 0) ? -3e38f : s1v[w][id0 >> 5] + s2v[w][id0 & 31];
  float v1 = (id1 < 0) ? -3e38f : s1v[w][id1 >> 5] + s2v[w][id1 & 31];

  // bitonic sort, descending by e. 28 compare-exchange stages.
#pragma unroll
  for (int kb = 1; kb <= 7; ++kb) {
    const int k = 1 << kb;
#pragma unroll
    for (int jb = kb - 1; jb >= 0; --jb) {
      const int j = 1 << jb;
      if (j == 64) {
        // in-thread CE between e=lane and e=64+lane (k=128: descending)
        if (v1 > v0) {
          const float tv = v0; v0 = v1; v1 = tv;
          const int ti = id0; id0 = id1; id1 = ti;
        }
      } else {
        {
          const int e = lane;
          const float ov = __shfl_xor(v0, j);
          const int oi = __shfl_xor(id0, j);
          const bool up = (e & k) != 0;
          const bool low = (e & j) == 0;
          const bool take = (low != up) ? (ov > v0) : (ov < v0);
          v0 = take ? ov : v0;
          id0 = take ? oi : id0;
        }
        {
          const int e = 64 + lane;
          const float ov = __shfl_xor(v1, j);
          const int oi = __shfl_xor(id1, j);
          const bool up = (e & k) != 0;
          const bool low = (e & j) == 0;
          const bool take = (low != up) ? (ov > v1) : (ov < v1);
          v1 = take ? ov : v1;
          id1 = take ? oi : id1;
        }
      }
    }
  }
  // lanes 0..31 of v0/id0 now hold the top-32 descending.

  const float m = __shfl(v0, 0);
  const float ev = __expf(v0 - m);
  float es = ev;
#pragma unroll
  for (int off = 16; off; off >>= 1) es += __shfl_xor(es, off);   // valid on lanes 0..31

  const int c0 = (id0 < 0) ? 0 : id0;
  const int mi = s1i[w][c0 >> 5] * NKEYS + s2i[w][c0 & 31];

  // gather: lane = g*32 + d; combo = 2*it + g
  const int g = lane >> 5, d = lane & 31;
  float acc = 0.f;
#pragma unroll
  for (int it = 0; it < 16; it++) {
    const int combo = 2 * it + g;
    const float wgt = __shfl(ev, combo);
    const int midx = __shfl(mi, combo);
    acc += wgt * values[(size_t)midx * VDIM + d];
  }
  acc += __shfl_xor(acc, 32);
  if (lane < 32) yh[w][d] = acc / es;
  __syncthreads();
  if (w == 0 && lane < 32) {
    y[(size_t)n * VDIM + lane] = yh[0][lane] + yh[1][lane] + yh[2][lane] + yh[3][lane];
  }
}

// ---------------------------------------------------------------------------
// K5: out = x + y @ W_r + b_r.  8 tokens per block; W_r columns reused in regs.
// ---------------------------------------------------------------------------
__global__ __launch_bounds__(256) void out_proj(const float* __restrict__ x,
                                                const float* __restrict__ yv,
                                                const float* __restrict__ Wr,
                                                const float* __restrict__ br,
                                                float* __restrict__ out) {
  const int nb = blockIdx.x * 8;
  const int t = threadIdx.x;
  __shared__ float ys[8][VDIM];
  ys[t >> 5][t & 31] = yv[(size_t)nb * VDIM + t];
  __syncthreads();

#pragma unroll
  for (int rep = 0; rep < 4; rep++) {
    const int d = t + rep * 256;
    float wcol[VDIM];
#pragma unroll
    for (int vv = 0; vv < VDIM; vv++) wcol[vv] = Wr[vv * DDIM + d];
    const float bb = br[d];
#pragma unroll 1
    for (int tok = 0; tok < 8; tok++) {
      float a = bb;
#pragma unroll
      for (int vv = 0; vv < VDIM; vv++) a = fmaf(ys[tok][vv], wcol[vv], a);
      const size_t o = (size_t)(nb + tok) * DDIM + d;
      out[o] = x[o] + a;
    }
  }
}

// ---------------------------------------------------------------------------
extern "C" void kernel_launch(void* const* d_in, const int* in_sizes, int n_in,
                              void* d_out, int out_size, void* d_ws, size_t ws_size,
                              hipStream_t stream) {
  const float* x      = (const float*)d_in[0];
  const float* W_q    = (const float*)d_in[1];
  const float* b_q    = (const float*)d_in[2];
  const float* keys   = (const float*)d_in[3];
  const float* values = (const float*)d_in[4];
  const float* W_r    = (const float*)d_in[5];
  const float* b_r    = (const float*)d_in[6];
  float* out = (float*)d_out;

  // Workspace layout
  unsigned short* qb    = (unsigned short*)d_ws;        // 8192*1024
  unsigned short* xb    = qb + (size_t)NTOK * DDIM;     // 8192*1024
  unsigned short* Wqt   = xb + (size_t)NTOK * DDIM;     // 1024*1024 (N x K)
  unsigned short* keysb = Wqt + (size_t)DDIM * DDIM;    // 8*1024*128
  float* sv = (float*)(keysb + (size_t)NHEADS * 2 * NKEYS * HALF);
  int*   si = (int*)(sv + (size_t)NTOK * NHEADS * 2 * KNN);
  float* y  = (float*)(si + (size_t)NTOK * NHEADS * 2 * KNN);
  float* sc = y + (size_t)NTOK * VDIM;                  // CHUNK*8*1024 f32

  // Convert inputs to bf16
  cvt_bf16<<<(NTOK * DDIM / 4 + 255) / 256, 256, 0, stream>>>(x, xb, NTOK * DDIM / 4);
  cvt_bf16<<<(NHEADS * 2 * NKEYS * HALF / 4 + 255) / 256, 256, 0, stream>>>(
      keys, keysb, NHEADS * 2 * NKEYS * HALF / 4);
  transpose_cvt<<<dim3(16, 16), 256, 0, stream>>>(W_q, Wqt);

  // K1: q = x @ W_q + b_q -> bf16   (8192x1024, K=1024)
  gemm_mfma<true, true><<<dim3(NTOK / 128, DDIM / 128, 1), 256, 0, stream>>>(
      xb, Wqt, b_q, qb, DDIM, DDIM, DDIM, DDIM, 0, 0, 0);

  // K2+K3 per chunk of tokens
  for (int ch = 0; ch < NTOK / CHUNK; ch++) {
    gemm_mfma<false, false><<<dim3(CHUNK / 128, NKEYS / 128, NHEADS * 2), 256, 0, stream>>>(
        qb + (size_t)ch * CHUNK * DDIM, keysb, nullptr, sc,
        HALF, DDIM, HALF, NHEADS * 2 * NKEYS,
        /*sAz=*/HALF, /*sBz=*/(long)NKEYS * HALF, /*sCz=*/NKEYS);
    topk_subkeys<<<CHUNK * NHEADS * 2 / 4, 256, 0, stream>>>(sc, sv, si, ch * CHUNK * NHEADS * 2);
  }

  // K4: staircase + bitonic top-32, softmax, value gather, head sum
  combine_topk2<<<NTOK, 256, 0, stream>>>(sv, si, values, y);

  // K5: out = x + y @ W_r + b_r
  out_proj<<<NTOK / 8, 256, 0, stream>>>(x, y, W_r, b_r, out);
}

// Round 7
// 756.825 us; speedup vs baseline: 1.9392x; 1.1714x over previous
//
#include <hip/hip_runtime.h>
#include <hip/hip_bf16.h>

// Problem constants
#define NTOK   8192      // B*T
#define DDIM   1024
#define NHEADS 4
#define KDIM   256
#define HALF   128
#define NKEYS  1024
#define KNN    32
#define VDIM   32
#define CHUNK  1024      // tokens per K2 z-slice

typedef __attribute__((ext_vector_type(8))) short bf16x8;
typedef __attribute__((ext_vector_type(4))) float f32x4;

__device__ __forceinline__ unsigned short f2bf(float f) {
  __hip_bfloat16 h = __float2bfloat16(f);
  return *reinterpret_cast<unsigned short*>(&h);
}

// async global->LDS, 16B per lane; LDS dest = wave-uniform base + lane*16
#define GLOAD_LDS16(g, l)                                             \
  __builtin_amdgcn_global_load_lds(                                   \
      (const __attribute__((address_space(1))) void*)(g),             \
      (__attribute__((address_space(3))) void*)(l), 16, 0, 0)

// ---------------------------------------------------------------------------
// Convert fp32 -> bf16 (flat, n multiple of 4)
// ---------------------------------------------------------------------------
__global__ __launch_bounds__(256) void cvt_bf16(const float* __restrict__ in,
                                                unsigned short* __restrict__ out, int n4) {
  int i = blockIdx.x * 256 + threadIdx.x;
  if (i >= n4) return;
  const float4 v = reinterpret_cast<const float4*>(in)[i];
  ushort4 o;
  o.x = f2bf(v.x); o.y = f2bf(v.y); o.z = f2bf(v.z); o.w = f2bf(v.w);
  reinterpret_cast<ushort4*>(out)[i] = o;
}

// ---------------------------------------------------------------------------
// W_q (K x N = 1024x1024) -> W_qT bf16 (N x K)
// ---------------------------------------------------------------------------
__global__ __launch_bounds__(256) void transpose_cvt(const float* __restrict__ W,
                                                     unsigned short* __restrict__ Wt) {
  __shared__ float t[64][65];
  const int bi = blockIdx.y, bj = blockIdx.x;
  const int tid = threadIdx.x;
  const int col = tid & 63;
#pragma unroll
  for (int p = 0; p < 16; p++) {
    const int row = p * 4 + (tid >> 6);
    t[row][col] = W[(size_t)(bi * 64 + row) * DDIM + bj * 64 + col];
  }
  __syncthreads();
#pragma unroll
  for (int p = 0; p < 16; p++) {
    const int row = p * 4 + (tid >> 6);
    Wt[(size_t)(bj * 64 + row) * DDIM + bi * 64 + col] = f2bf(t[col][row]);
  }
}

// ---------------------------------------------------------------------------
// bf16 MFMA GEMM: C[M,N] = A[M,K] * B[N,K]^T (+bias). 128x128 tile, BK=32,
// 256 threads = 4 waves (2x2 of 64x64), mfma_f32_16x16x32_bf16.
// Staging via global_load_lds width=16 into LINEAR LDS [128][32] (m97
// structure). LDS chunk c (16B) = row c>>2, k-chunk c&3; thread tid owns
// chunks tid and tid+256 -> LDS byte offset tid*16 (wave-uniform+lane*16).
// PKM: product-key mode. blockIdx.z = ch*8+hc; A += ch*CHUNK*DDIM + hc*HALF,
//      B += hc*NKEYS*HALF, C += ch*CHUNK*8192 + hc*NKEYS.
// ---------------------------------------------------------------------------
template <bool OBF, bool BIAS, bool PKM>
__global__ __launch_bounds__(256) void gemm_mfma(const unsigned short* __restrict__ A,
                                                 const unsigned short* __restrict__ B,
                                                 const float* __restrict__ bias,
                                                 void* __restrict__ Cv,
                                                 int K, int lda, int ldb, int ldc,
                                                 long sAz, long sBz, long sCz) {
  __shared__ unsigned short As[128 * 32];
  __shared__ unsigned short Bs[128 * 32];
  size_t Coff;
  if (PKM) {
    const int ch = blockIdx.z >> 3, hc = blockIdx.z & 7;
    A += (size_t)ch * CHUNK * DDIM + (size_t)hc * HALF;
    B += (size_t)hc * ((size_t)NKEYS * HALF);
    Coff = (size_t)ch * CHUNK * (NHEADS * 2 * NKEYS) + (size_t)hc * NKEYS;
  } else {
    A += (size_t)blockIdx.z * sAz;
    B += (size_t)blockIdx.z * sBz;
    Coff = (size_t)blockIdx.z * (size_t)sCz;
  }
  const int tid = threadIdx.x, lane = tid & 63, wv = tid >> 6;
  const int wr = wv >> 1, wc = wv & 1;
  const size_t bm = (size_t)blockIdx.x * 128;
  const size_t bn = (size_t)blockIdx.y * 128;

  // staging: 512 chunks of 8 bf16 per matrix; thread owns chunks tid, tid+256
  const int c0 = tid, c1 = tid + 256;
  const int r0 = c0 >> 2, k0c = (c0 & 3) * 8;
  const int r1 = c1 >> 2, k1c = (c1 & 3) * 8;
  const unsigned short* Ap0 = A + (bm + r0) * (size_t)lda + k0c;
  const unsigned short* Ap1 = A + (bm + r1) * (size_t)lda + k1c;
  const unsigned short* Bp0 = B + (bn + r0) * (size_t)ldb + k0c;
  const unsigned short* Bp1 = B + (bn + r1) * (size_t)ldb + k1c;
  // wave-uniform LDS bases (chunk index = wv*64 [+256], 8 ushorts per chunk)
  unsigned short* lA0 = As + (size_t)(wv * 64) * 8;
  unsigned short* lA1 = As + (size_t)(wv * 64 + 256) * 8;
  unsigned short* lB0 = Bs + (size_t)(wv * 64) * 8;
  unsigned short* lB1 = Bs + (size_t)(wv * 64 + 256) * 8;

  f32x4 acc[4][4];
#pragma unroll
  for (int m = 0; m < 4; m++)
#pragma unroll
    for (int n = 0; n < 4; n++) acc[m][n] = (f32x4){0.f, 0.f, 0.f, 0.f};

  const int fr = lane & 15;     // fragment row/col
  const int fk = lane >> 4;     // k-quarter (8 elems each)

  for (int kt = 0; kt < K; kt += 32) {
    __syncthreads();   // previous iteration's fragment reads done
    GLOAD_LDS16(Ap0 + kt, lA0);
    GLOAD_LDS16(Ap1 + kt, lA1);
    GLOAD_LDS16(Bp0 + kt, lB0);
    GLOAD_LDS16(Bp1 + kt, lB1);
    __syncthreads();   // barrier drains vmcnt -> tile ready

    bf16x8 af[4], bfv[4];
#pragma unroll
    for (int m = 0; m < 4; m++)
      af[m] = *reinterpret_cast<const bf16x8*>(&As[(wr * 64 + m * 16 + fr) * 32 + fk * 8]);
#pragma unroll
    for (int n = 0; n < 4; n++)
      bfv[n] = *reinterpret_cast<const bf16x8*>(&Bs[(wc * 64 + n * 16 + fr) * 32 + fk * 8]);
#pragma unroll
    for (int m = 0; m < 4; m++)
#pragma unroll
      for (int n = 0; n < 4; n++)
        acc[m][n] = __builtin_amdgcn_mfma_f32_16x16x32_bf16(af[m], bfv[n], acc[m][n], 0, 0, 0);
  }

  // epilogue: C/D layout col = lane&15, row = (lane>>4)*4 + q
#pragma unroll
  for (int n = 0; n < 4; n++) {
    const size_t col = bn + wc * 64 + n * 16 + fr;
    const float bv = BIAS ? bias[col] : 0.f;
#pragma unroll
    for (int m = 0; m < 4; m++) {
#pragma unroll
      for (int q = 0; q < 4; q++) {
        const size_t row = bm + wr * 64 + m * 16 + fk * 4 + q;
        const float val = acc[m][n][q] + bv;
        const size_t o = Coff + row * (size_t)ldc + col;
        if (OBF) ((unsigned short*)Cv)[o] = f2bf(val);
        else     ((float*)Cv)[o] = val;
      }
    }
  }
}

// ---------------------------------------------------------------------------
// K3: exact top-32 of 1024 scores per (n,h,c) group. One wave per group.
// Lane owns 16 CONTIGUOUS scores (idx = lane*16+j), loaded as 4x float4.
// Outputs values sorted descending + their indices. Single dispatch.
// ---------------------------------------------------------------------------
__global__ __launch_bounds__(256) void topk_subkeys(const float* __restrict__ sc,
                                                    float* __restrict__ sv,
                                                    int* __restrict__ si) {
  const int lane = threadIdx.x & 63;
  const int gl = blockIdx.x * 4 + (threadIdx.x >> 6);
  const float* s = sc + (size_t)gl * 1024;

  float v[16];
#pragma unroll
  for (int c = 0; c < 4; c++) {
    const float4 f = reinterpret_cast<const float4*>(s)[lane * 4 + c];
    v[c * 4 + 0] = f.x; v[c * 4 + 1] = f.y; v[c * 4 + 2] = f.z; v[c * 4 + 3] = f.w;
  }

  unsigned removed = 0u;
  const size_t gg = (size_t)gl;

#pragma unroll 1
  for (int it = 0; it < KNN; it++) {
    float best = -3e38f;
    int bj = 0;
#pragma unroll
    for (int j = 0; j < 16; j++) {
      const bool ok = (((removed >> j) & 1u) == 0u) && (v[j] > best);
      best = ok ? v[j] : best;
      bj = ok ? j : bj;
    }
    float wv = best;
    int wl = lane, wj = bj;
#pragma unroll
    for (int off = 32; off; off >>= 1) {
      const float ov = __shfl_xor(wv, off);
      const int ol = __shfl_xor(wl, off);
      const int oj = __shfl_xor(wj, off);
      const bool take = (ov > wv) || (ov == wv && ol < wl);
      wv = take ? ov : wv;
      wl = take ? ol : wl;
      wj = take ? oj : wj;
    }
    if (lane == wl) removed |= (1u << wj);
    if (lane == 0) {
      sv[gg * KNN + it] = wv;
      si[gg * KNN + it] = wl * 16 + wj;
    }
  }
}

// ---------------------------------------------------------------------------
// K4 v2: staircase candidates (119 of 1024) + bitonic sort of 128 across
// 64 lanes x 2 regs; softmax + value gather from sorted lanes.
// An element (i,j) of s1+s2 (both sorted desc) can be in the top-32 only if
// (i+1)*(j+1) <= 32: exactly 119 candidates.
// ---------------------------------------------------------------------------
__device__ const short CAND[128] = {
  // i=0: j=0..31
  0,1,2,3,4,5,6,7,8,9,10,11,12,13,14,15,16,17,18,19,20,21,22,23,24,25,26,27,28,29,30,31,
  // i=1: j=0..15
  32,33,34,35,36,37,38,39,40,41,42,43,44,45,46,47,
  // i=2: j=0..9
  64,65,66,67,68,69,70,71,72,73,
  // i=3: j=0..7
  96,97,98,99,100,101,102,103,
  // i=4: j=0..5
  128,129,130,131,132,133,
  // i=5: j=0..4
  160,161,162,163,164,
  // i=6: j=0..3
  192,193,194,195,
  // i=7: j=0..3
  224,225,226,227,
  // i=8,9: j=0..2
  256,257,258, 288,289,290,
  // i=10..15: j=0..1
  320,321, 352,353, 384,385, 416,417, 448,449, 480,481,
  // i=16..31: j=0
  512,544,576,608,640,672,704,736,768,800,832,864,896,928,960,992,
  // pad
  -1,-1,-1,-1,-1,-1,-1,-1,-1
};

__global__ __launch_bounds__(256) void combine_topk2(const float* __restrict__ sv,
                                                     const int* __restrict__ si,
                                                     const float* __restrict__ values,
                                                     float* __restrict__ y) {
  const int n = blockIdx.x;
  const int w = threadIdx.x >> 6;   // head
  const int lane = threadIdx.x & 63;

  __shared__ float s1v[4][32], s2v[4][32];
  __shared__ int s1i[4][32], s2i[4][32];
  __shared__ float yh[4][32];

  const size_t g1 = ((size_t)(n * 8 + w * 2)) * KNN;   // (n,h,c=0)
  const size_t g2 = g1 + KNN;                          // (n,h,c=1)
  if (lane < 32) {
    s1v[w][lane] = sv[g1 + lane];
    s1i[w][lane] = si[g1 + lane];
  } else {
    s2v[w][lane - 32] = sv[g2 + lane - 32];
    s2i[w][lane - 32] = si[g2 + lane - 32];
  }

  // candidate values: virtual index e = reg*64 + lane
  int id0 = CAND[lane], id1 = CAND[64 + lane];
  float v0 = (id0 < 0) ? -3e38f : s1v[w][id0 >> 5] + s2v[w][id0 & 31];
  float v1 = (id1 < 0) ? -3e38f : s1v[w][id1 >> 5] + s2v[w][id1 & 31];

  // bitonic sort, descending by e. 28 compare-exchange stages.
#pragma unroll
  for (int kb = 1; kb <= 7; ++kb) {
    const int k = 1 << kb;
#pragma unroll
    for (int jb = kb - 1; jb >= 0; --jb) {
      const int j = 1 << jb;
      if (j == 64) {
        // in-thread CE between e=lane and e=64+lane (k=128: descending)
        if (v1 > v0) {
          const float tv = v0; v0 = v1; v1 = tv;
          const int ti = id0; id0 = id1; id1 = ti;
        }
      } else {
        {
          const int e = lane;
          const float ov = __shfl_xor(v0, j);
          const int oi = __shfl_xor(id0, j);
          const bool up = (e & k) != 0;
          const bool low = (e & j) == 0;
          const bool take = (low != up) ? (ov > v0) : (ov < v0);
          v0 = take ? ov : v0;
          id0 = take ? oi : id0;
        }
        {
          const int e = 64 + lane;
          const float ov = __shfl_xor(v1, j);
          const int oi = __shfl_xor(id1, j);
          const bool up = (e & k) != 0;
          const bool low = (e & j) == 0;
          const bool take = (low != up) ? (ov > v1) : (ov < v1);
          v1 = take ? ov : v1;
          id1 = take ? oi : id1;
        }
      }
    }
  }
  // lanes 0..31 of v0/id0 now hold the top-32 descending.

  const float m = __shfl(v0, 0);
  const float ev = __expf(v0 - m);
  float es = ev;
#pragma unroll
  for (int off = 16; off; off >>= 1) es += __shfl_xor(es, off);   // valid on lanes 0..31

  const int c0 = (id0 < 0) ? 0 : id0;
  const int mi = s1i[w][c0 >> 5] * NKEYS + s2i[w][c0 & 31];

  // gather: lane = g*32 + d; combo = 2*it + g
  const int g = lane >> 5, d = lane & 31;
  float acc = 0.f;
#pragma unroll
  for (int it = 0; it < 16; it++) {
    const int combo = 2 * it + g;
    const float wgt = __shfl(ev, combo);
    const int midx = __shfl(mi, combo);
    acc += wgt * values[(size_t)midx * VDIM + d];
  }
  acc += __shfl_xor(acc, 32);
  if (lane < 32) yh[w][d] = acc / es;
  __syncthreads();
  if (w == 0 && lane < 32) {
    y[(size_t)n * VDIM + lane] = yh[0][lane] + yh[1][lane] + yh[2][lane] + yh[3][lane];
  }
}

// ---------------------------------------------------------------------------
// K5: out = x + y @ W_r + b_r.  8 tokens per block; W_r columns reused in regs.
// ---------------------------------------------------------------------------
__global__ __launch_bounds__(256) void out_proj(const float* __restrict__ x,
                                                const float* __restrict__ yv,
                                                const float* __restrict__ Wr,
                                                const float* __restrict__ br,
                                                float* __restrict__ out) {
  const int nb = blockIdx.x * 8;
  const int t = threadIdx.x;
  __shared__ float ys[8][VDIM];
  ys[t >> 5][t & 31] = yv[(size_t)nb * VDIM + t];
  __syncthreads();

#pragma unroll
  for (int rep = 0; rep < 4; rep++) {
    const int d = t + rep * 256;
    float wcol[VDIM];
#pragma unroll
    for (int vv = 0; vv < VDIM; vv++) wcol[vv] = Wr[vv * DDIM + d];
    const float bb = br[d];
#pragma unroll 1
    for (int tok = 0; tok < 8; tok++) {
      float a = bb;
#pragma unroll
      for (int vv = 0; vv < VDIM; vv++) a = fmaf(ys[tok][vv], wcol[vv], a);
      const size_t o = (size_t)(nb + tok) * DDIM + d;
      out[o] = x[o] + a;
    }
  }
}

// ---------------------------------------------------------------------------
extern "C" void kernel_launch(void* const* d_in, const int* in_sizes, int n_in,
                              void* d_out, int out_size, void* d_ws, size_t ws_size,
                              hipStream_t stream) {
  const float* x      = (const float*)d_in[0];
  const float* W_q    = (const float*)d_in[1];
  const float* b_q    = (const float*)d_in[2];
  const float* keys   = (const float*)d_in[3];
  const float* values = (const float*)d_in[4];
  const float* W_r    = (const float*)d_in[5];
  const float* b_r    = (const float*)d_in[6];
  float* out = (float*)d_out;

  // Workspace layout (512 MiB available; total used ~332 MB)
  unsigned short* qb    = (unsigned short*)d_ws;        // 8192*1024 bf16
  unsigned short* xb    = qb + (size_t)NTOK * DDIM;     // 8192*1024 bf16
  unsigned short* Wqt   = xb + (size_t)NTOK * DDIM;     // 1024*1024 bf16 (N x K)
  unsigned short* keysb = Wqt + (size_t)DDIM * DDIM;    // 8*1024*128 bf16
  float* sv = (float*)(keysb + (size_t)NHEADS * 2 * NKEYS * HALF);
  int*   si = (int*)(sv + (size_t)NTOK * NHEADS * 2 * KNN);
  float* y  = (float*)(si + (size_t)NTOK * NHEADS * 2 * KNN);
  float* sc = y + (size_t)NTOK * VDIM;                  // 8192 * 8192 f32 (268 MB)

  // Convert inputs to bf16
  cvt_bf16<<<(NTOK * DDIM / 4 + 255) / 256, 256, 0, stream>>>(x, xb, NTOK * DDIM / 4);
  cvt_bf16<<<(NHEADS * 2 * NKEYS * HALF / 4 + 255) / 256, 256, 0, stream>>>(
      keys, keysb, NHEADS * 2 * NKEYS * HALF / 4);
  transpose_cvt<<<dim3(16, 16), 256, 0, stream>>>(W_q, Wqt);

  // K1: q = x @ W_q + b_q -> bf16   (8192x1024, K=1024)
  gemm_mfma<true, true, false><<<dim3(NTOK / 128, DDIM / 128, 1), 256, 0, stream>>>(
      xb, Wqt, b_q, qb, DDIM, DDIM, DDIM, DDIM, 0, 0, 0);

  // K2: all chunks+head-halves in one dispatch. z = ch*8 + hc.
  // sc[n][hc][key], row stride 8192.
  gemm_mfma<false, false, true><<<dim3(CHUNK / 128, NKEYS / 128, (NTOK / CHUNK) * NHEADS * 2),
                                  256, 0, stream>>>(
      qb, keysb, nullptr, sc, HALF, DDIM, HALF, NHEADS * 2 * NKEYS, 0, 0, 0);

  // K3: top-32 per (n,hc) group, all 65536 groups in one dispatch
  topk_subkeys<<<NTOK * NHEADS * 2 / 4, 256, 0, stream>>>(sc, sv, si);

  // K4: staircase + bitonic top-32, softmax, value gather, head sum
  combine_topk2<<<NTOK, 256, 0, stream>>>(sv, si, values, y);

  // K5: out = x + y @ W_r + b_r
  out_proj<<<NTOK / 8, 256, 0, stream>>>(x, y, W_r, b_r, out);
}

// Round 9
// 510.036 us; speedup vs baseline: 2.8775x; 1.4839x over previous
//
#include <hip/hip_runtime.h>
#include <hip/hip_bf16.h>

// Problem constants
#define NTOK   8192      // B*T
#define DDIM   1024
#define NHEADS 4
#define KDIM   256
#define HALF   128
#define NKEYS  1024
#define KNN    32
#define VDIM   32
#define CHUNK  1024      // tokens per K2 z-slice

typedef __attribute__((ext_vector_type(8))) short bf16x8;
typedef __attribute__((ext_vector_type(4))) float f32x4;

__device__ __forceinline__ unsigned short f2bf(float f) {
  __hip_bfloat16 h = __float2bfloat16(f);
  return *reinterpret_cast<unsigned short*>(&h);
}

// async global->LDS, 16B per lane; LDS dest = wave-uniform base + lane*16
#define GLOAD_LDS16(g, l)                                             \
  __builtin_amdgcn_global_load_lds(                                   \
      (const __attribute__((address_space(1))) void*)(g),             \
      (__attribute__((address_space(3))) void*)(l), 16, 0, 0)

// ---------------------------------------------------------------------------
// Convert fp32 -> bf16 (flat, n multiple of 4)
// ---------------------------------------------------------------------------
__global__ __launch_bounds__(256) void cvt_bf16(const float* __restrict__ in,
                                                unsigned short* __restrict__ out, int n4) {
  int i = blockIdx.x * 256 + threadIdx.x;
  if (i >= n4) return;
  const float4 v = reinterpret_cast<const float4*>(in)[i];
  ushort4 o;
  o.x = f2bf(v.x); o.y = f2bf(v.y); o.z = f2bf(v.z); o.w = f2bf(v.w);
  reinterpret_cast<ushort4*>(out)[i] = o;
}

// ---------------------------------------------------------------------------
// W_q (K x N = 1024x1024) -> W_qT bf16 (N x K)
// ---------------------------------------------------------------------------
__global__ __launch_bounds__(256) void transpose_cvt(const float* __restrict__ W,
                                                     unsigned short* __restrict__ Wt) {
  __shared__ float t[64][65];
  const int bi = blockIdx.y, bj = blockIdx.x;
  const int tid = threadIdx.x;
  const int col = tid & 63;
#pragma unroll
  for (int p = 0; p < 16; p++) {
    const int row = p * 4 + (tid >> 6);
    t[row][col] = W[(size_t)(bi * 64 + row) * DDIM + bj * 64 + col];
  }
  __syncthreads();
#pragma unroll
  for (int p = 0; p < 16; p++) {
    const int row = p * 4 + (tid >> 6);
    Wt[(size_t)(bj * 64 + row) * DDIM + bi * 64 + col] = f2bf(t[col][row]);
  }
}

// ---------------------------------------------------------------------------
// bf16 MFMA GEMM: C[M,N] = A[M,K] * B[N,K]^T (+bias). 128x128 tile, BK=32,
// 256 threads = 4 waves (2x2 of 64x64), mfma_f32_16x16x32_bf16.
// Staging via global_load_lds width=16 into LINEAR LDS [128][32] (m97
// structure). PKM: product-key mode (blockIdx.z = ch*8+hc).
// ---------------------------------------------------------------------------
template <bool OBF, bool BIAS, bool PKM>
__global__ __launch_bounds__(256) void gemm_mfma(const unsigned short* __restrict__ A,
                                                 const unsigned short* __restrict__ B,
                                                 const float* __restrict__ bias,
                                                 void* __restrict__ Cv,
                                                 int K, int lda, int ldb, int ldc,
                                                 long sAz, long sBz, long sCz) {
  __shared__ unsigned short As[128 * 32];
  __shared__ unsigned short Bs[128 * 32];
  size_t Coff;
  if (PKM) {
    const int ch = blockIdx.z >> 3, hc = blockIdx.z & 7;
    A += (size_t)ch * CHUNK * DDIM + (size_t)hc * HALF;
    B += (size_t)hc * ((size_t)NKEYS * HALF);
    Coff = (size_t)ch * CHUNK * (NHEADS * 2 * NKEYS) + (size_t)hc * NKEYS;
  } else {
    A += (size_t)blockIdx.z * sAz;
    B += (size_t)blockIdx.z * sBz;
    Coff = (size_t)blockIdx.z * (size_t)sCz;
  }
  const int tid = threadIdx.x, lane = tid & 63, wv = tid >> 6;
  const int wr = wv >> 1, wc = wv & 1;
  const size_t bm = (size_t)blockIdx.x * 128;
  const size_t bn = (size_t)blockIdx.y * 128;

  // staging: 512 chunks of 8 bf16 per matrix; thread owns chunks tid, tid+256
  const int c0 = tid, c1 = tid + 256;
  const int r0 = c0 >> 2, k0c = (c0 & 3) * 8;
  const int r1 = c1 >> 2, k1c = (c1 & 3) * 8;
  const unsigned short* Ap0 = A + (bm + r0) * (size_t)lda + k0c;
  const unsigned short* Ap1 = A + (bm + r1) * (size_t)lda + k1c;
  const unsigned short* Bp0 = B + (bn + r0) * (size_t)ldb + k0c;
  const unsigned short* Bp1 = B + (bn + r1) * (size_t)ldb + k1c;
  // wave-uniform LDS bases (chunk index = wv*64 [+256], 8 ushorts per chunk)
  unsigned short* lA0 = As + (size_t)(wv * 64) * 8;
  unsigned short* lA1 = As + (size_t)(wv * 64 + 256) * 8;
  unsigned short* lB0 = Bs + (size_t)(wv * 64) * 8;
  unsigned short* lB1 = Bs + (size_t)(wv * 64 + 256) * 8;

  f32x4 acc[4][4];
#pragma unroll
  for (int m = 0; m < 4; m++)
#pragma unroll
    for (int n = 0; n < 4; n++) acc[m][n] = (f32x4){0.f, 0.f, 0.f, 0.f};

  const int fr = lane & 15;     // fragment row/col
  const int fk = lane >> 4;     // k-quarter (8 elems each)

  for (int kt = 0; kt < K; kt += 32) {
    __syncthreads();   // previous iteration's fragment reads done
    GLOAD_LDS16(Ap0 + kt, lA0);
    GLOAD_LDS16(Ap1 + kt, lA1);
    GLOAD_LDS16(Bp0 + kt, lB0);
    GLOAD_LDS16(Bp1 + kt, lB1);
    __syncthreads();   // barrier drains vmcnt -> tile ready

    bf16x8 af[4], bfv[4];
#pragma unroll
    for (int m = 0; m < 4; m++)
      af[m] = *reinterpret_cast<const bf16x8*>(&As[(wr * 64 + m * 16 + fr) * 32 + fk * 8]);
#pragma unroll
    for (int n = 0; n < 4; n++)
      bfv[n] = *reinterpret_cast<const bf16x8*>(&Bs[(wc * 64 + n * 16 + fr) * 32 + fk * 8]);
#pragma unroll
    for (int m = 0; m < 4; m++)
#pragma unroll
      for (int n = 0; n < 4; n++)
        acc[m][n] = __builtin_amdgcn_mfma_f32_16x16x32_bf16(af[m], bfv[n], acc[m][n], 0, 0, 0);
  }

  // epilogue: C/D layout col = lane&15, row = (lane>>4)*4 + q
#pragma unroll
  for (int n = 0; n < 4; n++) {
    const size_t col = bn + wc * 64 + n * 16 + fr;
    const float bv = BIAS ? bias[col] : 0.f;
#pragma unroll
    for (int m = 0; m < 4; m++) {
#pragma unroll
      for (int q = 0; q < 4; q++) {
        const size_t row = bm + wr * 64 + m * 16 + fk * 4 + q;
        const float val = acc[m][n][q] + bv;
        const size_t o = Coff + row * (size_t)ldc + col;
        if (OBF) ((unsigned short*)Cv)[o] = f2bf(val);
        else     ((float*)Cv)[o] = val;
      }
    }
  }
}

// ---------------------------------------------------------------------------
// K3 v2: packed-key top-32 of 1024 per group. One wave per group.
// key = (orderedU32(score) & 0xFFFFFC00) | (1023 - gidx): selection by
// (22-bit value, lower-index-first) — matches jax tie-break; value error
// <= 2^-13 relative. Per-lane bitonic sort-16 (static min/max network),
// then 32x {single-u32 butterfly max; winner lane shifts its list}.
// ---------------------------------------------------------------------------
__global__ __launch_bounds__(256) void topk_subkeys(const float* __restrict__ sc,
                                                    float* __restrict__ sv,
                                                    int* __restrict__ si) {
  const int lane = threadIdx.x & 63;
  const int gl = blockIdx.x * 4 + (threadIdx.x >> 6);
  const float* s = sc + (size_t)gl * 1024;

  unsigned key[16];
#pragma unroll
  for (int c = 0; c < 4; c++) {
    const float4 f = reinterpret_cast<const float4*>(s)[lane * 4 + c];
    const float ff[4] = {f.x, f.y, f.z, f.w};
#pragma unroll
    for (int e = 0; e < 4; e++) {
      unsigned u = __float_as_uint(ff[e]);
      u = (u & 0x80000000u) ? ~u : (u | 0x80000000u);
      key[c * 4 + e] = (u & 0xFFFFFC00u) | (unsigned)(1023 - (lane * 16 + c * 4 + e));
    }
  }

  // in-register bitonic sort, descending (all indices static)
#pragma unroll
  for (int k = 2; k <= 16; k <<= 1) {
#pragma unroll
    for (int j = k >> 1; j > 0; j >>= 1) {
#pragma unroll
      for (int i = 0; i < 16; i++) {
        const int l = i ^ j;
        if (l > i) {
          const unsigned a = key[i], b = key[l];
          const unsigned hi = a > b ? a : b, lo = a > b ? b : a;
          const bool desc = ((i & k) == 0);
          key[i] = desc ? hi : lo;
          key[l] = desc ? lo : hi;
        }
      }
    }
  }

  float* svp = sv + (size_t)gl * KNN;
  int* sip = si + (size_t)gl * KNN;

#pragma unroll 1
  for (int it = 0; it < KNN; it++) {
    unsigned w = key[0];
#pragma unroll
    for (int off = 1; off < 64; off <<= 1) {
      const unsigned o = __shfl_xor(w, off);
      w = o > w ? o : w;
    }
    const int gidx = 1023 - (int)(w & 1023u);
    if (lane == 0) {
      const unsigned u = w & 0xFFFFFC00u;
      svp[it] = (u & 0x80000000u) ? __uint_as_float(u ^ 0x80000000u)
                                  : __uint_as_float(~u);
      sip[it] = gidx;
    }
    const bool me = (lane == (gidx >> 4));
#pragma unroll
    for (int j = 0; j < 15; j++) key[j] = me ? key[j + 1] : key[j];
    key[15] = me ? 0u : key[15];
  }
}

// ---------------------------------------------------------------------------
// K4 v2: staircase candidates (119 of 1024) + bitonic sort of 128 across
// 64 lanes x 2 regs; softmax + value gather from sorted lanes.
// An element (i,j) of s1+s2 (both sorted desc) can be in the top-32 only if
// (i+1)*(j+1) <= 32: exactly 119 candidates.
// ---------------------------------------------------------------------------
__device__ const short CAND[128] = {
  // i=0: j=0..31
  0,1,2,3,4,5,6,7,8,9,10,11,12,13,14,15,16,17,18,19,20,21,22,23,24,25,26,27,28,29,30,31,
  // i=1: j=0..15
  32,33,34,35,36,37,38,39,40,41,42,43,44,45,46,47,
  // i=2: j=0..9
  64,65,66,67,68,69,70,71,72,73,
  // i=3: j=0..7
  96,97,98,99,100,101,102,103,
  // i=4: j=0..5
  128,129,130,131,132,133,
  // i=5: j=0..4
  160,161,162,163,164,
  // i=6: j=0..3
  192,193,194,195,
  // i=7: j=0..3
  224,225,226,227,
  // i=8,9: j=0..2
  256,257,258, 288,289,290,
  // i=10..15: j=0..1
  320,321, 352,353, 384,385, 416,417, 448,449, 480,481,
  // i=16..31: j=0
  512,544,576,608,640,672,704,736,768,800,832,864,896,928,960,992,
  // pad
  -1,-1,-1,-1,-1,-1,-1,-1,-1
};

__global__ __launch_bounds__(256) void combine_topk2(const float* __restrict__ sv,
                                                     const int* __restrict__ si,
                                                     const float* __restrict__ values,
                                                     float* __restrict__ y) {
  const int n = blockIdx.x;
  const int w = threadIdx.x >> 6;   // head
  const int lane = threadIdx.x & 63;

  __shared__ float s1v[4][32], s2v[4][32];
  __shared__ int s1i[4][32], s2i[4][32];
  __shared__ float yh[4][32];

  const size_t g1 = ((size_t)(n * 8 + w * 2)) * KNN;   // (n,h,c=0)
  const size_t g2 = g1 + KNN;                          // (n,h,c=1)
  if (lane < 32) {
    s1v[w][lane] = sv[g1 + lane];
    s1i[w][lane] = si[g1 + lane];
  } else {
    s2v[w][lane - 32] = sv[g2 + lane - 32];
    s2i[w][lane - 32] = si[g2 + lane - 32];
  }

  // candidate values: virtual index e = reg*64 + lane
  int id0 = CAND[lane], id1 = CAND[64 + lane];
  float v0 = (id0 < 0) ? -3e38f : s1v[w][id0 >> 5] + s2v[w][id0 & 31];
  float v1 = (id1 < 0) ? -3e38f : s1v[w][id1 >> 5] + s2v[w][id1 & 31];

  // bitonic sort, descending by e. 28 compare-exchange stages.
#pragma unroll
  for (int kb = 1; kb <= 7; ++kb) {
    const int k = 1 << kb;
#pragma unroll
    for (int jb = kb - 1; jb >= 0; --jb) {
      const int j = 1 << jb;
      if (j == 64) {
        // in-thread CE between e=lane and e=64+lane (k=128: descending)
        if (v1 > v0) {
          const float tv = v0; v0 = v1; v1 = tv;
          const int ti = id0; id0 = id1; id1 = ti;
        }
      } else {
        {
          const int e = lane;
          const float ov = __shfl_xor(v0, j);
          const int oi = __shfl_xor(id0, j);
          const bool up = (e & k) != 0;
          const bool low = (e & j) == 0;
          const bool take = (low != up) ? (ov > v0) : (ov < v0);
          v0 = take ? ov : v0;
          id0 = take ? oi : id0;
        }
        {
          const int e = 64 + lane;
          const float ov = __shfl_xor(v1, j);
          const int oi = __shfl_xor(id1, j);
          const bool up = (e & k) != 0;
          const bool low = (e & j) == 0;
          const bool take = (low != up) ? (ov > v1) : (ov < v1);
          v1 = take ? ov : v1;
          id1 = take ? oi : id1;
        }
      }
    }
  }
  // lanes 0..31 of v0/id0 now hold the top-32 descending.

  const float m = __shfl(v0, 0);
  const float ev = __expf(v0 - m);
  float es = ev;
#pragma unroll
  for (int off = 16; off; off >>= 1) es += __shfl_xor(es, off);   // valid on lanes 0..31

  const int c0 = (id0 < 0) ? 0 : id0;
  const int mi = s1i[w][c0 >> 5] * NKEYS + s2i[w][c0 & 31];

  // gather: lane = g*32 + d; combo = 2*it + g
  const int g = lane >> 5, d = lane & 31;
  float acc = 0.f;
#pragma unroll
  for (int it = 0; it < 16; it++) {
    const int combo = 2 * it + g;
    const float wgt = __shfl(ev, combo);
    const int midx = __shfl(mi, combo);
    acc += wgt * values[(size_t)midx * VDIM + d];
  }
  acc += __shfl_xor(acc, 32);
  if (lane < 32) yh[w][d] = acc / es;
  __syncthreads();
  if (w == 0 && lane < 32) {
    y[(size_t)n * VDIM + lane] = yh[0][lane] + yh[1][lane] + yh[2][lane] + yh[3][lane];
  }
}

// ---------------------------------------------------------------------------
// K5: out = x + y @ W_r + b_r.  8 tokens per block; W_r columns reused in regs.
// ---------------------------------------------------------------------------
__global__ __launch_bounds__(256) void out_proj(const float* __restrict__ x,
                                                const float* __restrict__ yv,
                                                const float* __restrict__ Wr,
                                                const float* __restrict__ br,
                                                float* __restrict__ out) {
  const int nb = blockIdx.x * 8;
  const int t = threadIdx.x;
  __shared__ float ys[8][VDIM];
  ys[t >> 5][t & 31] = yv[(size_t)nb * VDIM + t];
  __syncthreads();

#pragma unroll
  for (int rep = 0; rep < 4; rep++) {
    const int d = t + rep * 256;
    float wcol[VDIM];
#pragma unroll
    for (int vv = 0; vv < VDIM; vv++) wcol[vv] = Wr[vv * DDIM + d];
    const float bb = br[d];
#pragma unroll 1
    for (int tok = 0; tok < 8; tok++) {
      float a = bb;
#pragma unroll
      for (int vv = 0; vv < VDIM; vv++) a = fmaf(ys[tok][vv], wcol[vv], a);
      const size_t o = (size_t)(nb + tok) * DDIM + d;
      out[o] = x[o] + a;
    }
  }
}

// ---------------------------------------------------------------------------
extern "C" void kernel_launch(void* const* d_in, const int* in_sizes, int n_in,
                              void* d_out, int out_size, void* d_ws, size_t ws_size,
                              hipStream_t stream) {
  const float* x      = (const float*)d_in[0];
  const float* W_q    = (const float*)d_in[1];
  const float* b_q    = (const float*)d_in[2];
  const float* keys   = (const float*)d_in[3];
  const float* values = (const float*)d_in[4];
  const float* W_r    = (const float*)d_in[5];
  const float* b_r    = (const float*)d_in[6];
  float* out = (float*)d_out;

  // Workspace layout (512 MiB available; total used ~332 MB)
  unsigned short* qb    = (unsigned short*)d_ws;        // 8192*1024 bf16
  unsigned short* xb    = qb + (size_t)NTOK * DDIM;     // 8192*1024 bf16
  unsigned short* Wqt   = xb + (size_t)NTOK * DDIM;     // 1024*1024 bf16 (N x K)
  unsigned short* keysb = Wqt + (size_t)DDIM * DDIM;    // 8*1024*128 bf16
  float* sv = (float*)(keysb + (size_t)NHEADS * 2 * NKEYS * HALF);
  int*   si = (int*)(sv + (size_t)NTOK * NHEADS * 2 * KNN);
  float* y  = (float*)(si + (size_t)NTOK * NHEADS * 2 * KNN);
  float* sc = y + (size_t)NTOK * VDIM;                  // 8192 * 8192 f32 (268 MB)

  // Convert inputs to bf16
  cvt_bf16<<<(NTOK * DDIM / 4 + 255) / 256, 256, 0, stream>>>(x, xb, NTOK * DDIM / 4);
  cvt_bf16<<<(NHEADS * 2 * NKEYS * HALF / 4 + 255) / 256, 256, 0, stream>>>(
      keys, keysb, NHEADS * 2 * NKEYS * HALF / 4);
  transpose_cvt<<<dim3(16, 16), 256, 0, stream>>>(W_q, Wqt);

  // K1: q = x @ W_q + b_q -> bf16   (8192x1024, K=1024)
  gemm_mfma<true, true, false><<<dim3(NTOK / 128, DDIM / 128, 1), 256, 0, stream>>>(
      xb, Wqt, b_q, qb, DDIM, DDIM, DDIM, DDIM, 0, 0, 0);

  // K2: all chunks+head-halves in one dispatch. z = ch*8 + hc.
  // sc[n][hc][key], row stride 8192.
  gemm_mfma<false, false, true><<<dim3(CHUNK / 128, NKEYS / 128, (NTOK / CHUNK) * NHEADS * 2),
                                  256, 0, stream>>>(
      qb, keysb, nullptr, sc, HALF, DDIM, HALF, NHEADS * 2 * NKEYS, 0, 0, 0);

  // K3: top-32 per (n,hc) group, all 65536 groups in one dispatch
  topk_subkeys<<<NTOK * NHEADS * 2 / 4, 256, 0, stream>>>(sc, sv, si);

  // K4: staircase + bitonic top-32, softmax, value gather, head sum
  combine_topk2<<<NTOK, 256, 0, stream>>>(sv, si, values, y);

  // K5: out = x + y @ W_r + b_r
  out_proj<<<NTOK / 8, 256, 0, stream>>>(x, y, W_r, b_r, out);
}

// Round 10
// 492.955 us; speedup vs baseline: 2.9772x; 1.0347x over previous
//
#include <hip/hip_runtime.h>
#include <hip/hip_bf16.h>

// Problem constants
#define NTOK   8192      // B*T
#define DDIM   1024
#define NHEADS 4
#define KDIM   256
#define HALF   128
#define NKEYS  1024
#define KNN    32
#define VDIM   32
#define CHUNK  1024      // tokens per K2 z-slice

typedef __attribute__((ext_vector_type(8))) short bf16x8;
typedef __attribute__((ext_vector_type(4))) float f32x4;

__device__ __forceinline__ unsigned short f2bf(float f) {
  __hip_bfloat16 h = __float2bfloat16(f);
  return *reinterpret_cast<unsigned short*>(&h);
}

// decode packed key -> score (bf16 value in high bits)
__device__ __forceinline__ float dec_key(unsigned k) {
  const unsigned ord = (k >> 10) & 0xFFFFu;
  const unsigned v16 = (ord & 0x8000u) ? (ord ^ 0x8000u) : (ord ^ 0xFFFFu);
  return __uint_as_float(v16 << 16);
}

// async global->LDS, 16B per lane; LDS dest = wave-uniform base + lane*16
#define GLOAD_LDS16(g, l)                                             \
  __builtin_amdgcn_global_load_lds(                                   \
      (const __attribute__((address_space(1))) void*)(g),             \
      (__attribute__((address_space(3))) void*)(l), 16, 0, 0)

// ---------------------------------------------------------------------------
// Convert fp32 -> bf16 (flat, n multiple of 4)
// ---------------------------------------------------------------------------
__global__ __launch_bounds__(256) void cvt_bf16(const float* __restrict__ in,
                                                unsigned short* __restrict__ out, int n4) {
  int i = blockIdx.x * 256 + threadIdx.x;
  if (i >= n4) return;
  const float4 v = reinterpret_cast<const float4*>(in)[i];
  ushort4 o;
  o.x = f2bf(v.x); o.y = f2bf(v.y); o.z = f2bf(v.z); o.w = f2bf(v.w);
  reinterpret_cast<ushort4*>(out)[i] = o;
}

// ---------------------------------------------------------------------------
// W_q (K x N = 1024x1024) -> W_qT bf16 (N x K)
// ---------------------------------------------------------------------------
__global__ __launch_bounds__(256) void transpose_cvt(const float* __restrict__ W,
                                                     unsigned short* __restrict__ Wt) {
  __shared__ float t[64][65];
  const int bi = blockIdx.y, bj = blockIdx.x;
  const int tid = threadIdx.x;
  const int col = tid & 63;
#pragma unroll
  for (int p = 0; p < 16; p++) {
    const int row = p * 4 + (tid >> 6);
    t[row][col] = W[(size_t)(bi * 64 + row) * DDIM + bj * 64 + col];
  }
  __syncthreads();
#pragma unroll
  for (int p = 0; p < 16; p++) {
    const int row = p * 4 + (tid >> 6);
    Wt[(size_t)(bj * 64 + row) * DDIM + bi * 64 + col] = f2bf(t[col][row]);
  }
}

// ---------------------------------------------------------------------------
// bf16 MFMA GEMM: C[M,N] = A[M,K] * B[N,K]^T (+bias). 128x128 tile, BK=32,
// 256 threads = 4 waves (2x2 of 64x64), mfma_f32_16x16x32_bf16.
// Staging via global_load_lds width=16 into LINEAR LDS [128][32] (m97
// structure). PKM: product-key mode (blockIdx.z = ch*8+hc).
// ---------------------------------------------------------------------------
template <bool OBF, bool BIAS, bool PKM>
__global__ __launch_bounds__(256) void gemm_mfma(const unsigned short* __restrict__ A,
                                                 const unsigned short* __restrict__ B,
                                                 const float* __restrict__ bias,
                                                 void* __restrict__ Cv,
                                                 int K, int lda, int ldb, int ldc,
                                                 long sAz, long sBz, long sCz) {
  __shared__ unsigned short As[128 * 32];
  __shared__ unsigned short Bs[128 * 32];
  size_t Coff;
  if (PKM) {
    const int ch = blockIdx.z >> 3, hc = blockIdx.z & 7;
    A += (size_t)ch * CHUNK * DDIM + (size_t)hc * HALF;
    B += (size_t)hc * ((size_t)NKEYS * HALF);
    Coff = (size_t)ch * CHUNK * (NHEADS * 2 * NKEYS) + (size_t)hc * NKEYS;
  } else {
    A += (size_t)blockIdx.z * sAz;
    B += (size_t)blockIdx.z * sBz;
    Coff = (size_t)blockIdx.z * (size_t)sCz;
  }
  const int tid = threadIdx.x, lane = tid & 63, wv = tid >> 6;
  const int wr = wv >> 1, wc = wv & 1;
  const size_t bm = (size_t)blockIdx.x * 128;
  const size_t bn = (size_t)blockIdx.y * 128;

  // staging: 512 chunks of 8 bf16 per matrix; thread owns chunks tid, tid+256
  const int c0 = tid, c1 = tid + 256;
  const int r0 = c0 >> 2, k0c = (c0 & 3) * 8;
  const int r1 = c1 >> 2, k1c = (c1 & 3) * 8;
  const unsigned short* Ap0 = A + (bm + r0) * (size_t)lda + k0c;
  const unsigned short* Ap1 = A + (bm + r1) * (size_t)lda + k1c;
  const unsigned short* Bp0 = B + (bn + r0) * (size_t)ldb + k0c;
  const unsigned short* Bp1 = B + (bn + r1) * (size_t)ldb + k1c;
  // wave-uniform LDS bases (chunk index = wv*64 [+256], 8 ushorts per chunk)
  unsigned short* lA0 = As + (size_t)(wv * 64) * 8;
  unsigned short* lA1 = As + (size_t)(wv * 64 + 256) * 8;
  unsigned short* lB0 = Bs + (size_t)(wv * 64) * 8;
  unsigned short* lB1 = Bs + (size_t)(wv * 64 + 256) * 8;

  f32x4 acc[4][4];
#pragma unroll
  for (int m = 0; m < 4; m++)
#pragma unroll
    for (int n = 0; n < 4; n++) acc[m][n] = (f32x4){0.f, 0.f, 0.f, 0.f};

  const int fr = lane & 15;     // fragment row/col
  const int fk = lane >> 4;     // k-quarter (8 elems each)

  for (int kt = 0; kt < K; kt += 32) {
    __syncthreads();   // previous iteration's fragment reads done
    GLOAD_LDS16(Ap0 + kt, lA0);
    GLOAD_LDS16(Ap1 + kt, lA1);
    GLOAD_LDS16(Bp0 + kt, lB0);
    GLOAD_LDS16(Bp1 + kt, lB1);
    __syncthreads();   // barrier drains vmcnt -> tile ready

    bf16x8 af[4], bfv[4];
#pragma unroll
    for (int m = 0; m < 4; m++)
      af[m] = *reinterpret_cast<const bf16x8*>(&As[(wr * 64 + m * 16 + fr) * 32 + fk * 8]);
#pragma unroll
    for (int n = 0; n < 4; n++)
      bfv[n] = *reinterpret_cast<const bf16x8*>(&Bs[(wc * 64 + n * 16 + fr) * 32 + fk * 8]);
#pragma unroll
    for (int m = 0; m < 4; m++)
#pragma unroll
      for (int n = 0; n < 4; n++)
        acc[m][n] = __builtin_amdgcn_mfma_f32_16x16x32_bf16(af[m], bfv[n], acc[m][n], 0, 0, 0);
  }

  // epilogue: C/D layout col = lane&15, row = (lane>>4)*4 + q
#pragma unroll
  for (int n = 0; n < 4; n++) {
    const size_t col = bn + wc * 64 + n * 16 + fr;
    const float bv = BIAS ? bias[col] : 0.f;
#pragma unroll
    for (int m = 0; m < 4; m++) {
#pragma unroll
      for (int q = 0; q < 4; q++) {
        const size_t row = bm + wr * 64 + m * 16 + fk * 4 + q;
        const float val = acc[m][n][q] + bv;
        const size_t o = Coff + row * (size_t)ldc + col;
        if (OBF) ((unsigned short*)Cv)[o] = f2bf(val);
        else     ((float*)Cv)[o] = val;
      }
    }
  }
}

// ---------------------------------------------------------------------------
// K3 v3: packed-key top-32 of 1024 bf16 scores per group. One wave/group.
// key = ord16(score)<<10 | (1023-gidx): 26 bits, globally unique, ties ->
// lower index (jax semantics). Per-lane bitonic sort-16; tail key[1..15]
// + zero sentinel stashed in LDS; extraction = 6-step max butterfly +
// winner (h==w) pops next head via ds_read (no register shift chain).
// Output: packed keys (K4 decodes).
// ---------------------------------------------------------------------------
__global__ __launch_bounds__(256) void topk_subkeys(const unsigned short* __restrict__ sc,
                                                    unsigned* __restrict__ ski) {
  __shared__ unsigned heads[4][17][64];
  const int lane = threadIdx.x & 63;
  const int wv = threadIdx.x >> 6;
  const int gl = blockIdx.x * 4 + wv;
  const unsigned* s32 = (const unsigned*)(sc + (size_t)gl * 1024 + lane * 16);

  unsigned key[16];
  {
    const uint4 p0 = reinterpret_cast<const uint4*>(s32)[0];
    const uint4 p1 = reinterpret_cast<const uint4*>(s32)[1];
    const unsigned wds[8] = {p0.x, p0.y, p0.z, p0.w, p1.x, p1.y, p1.z, p1.w};
    const int base = 1023 - lane * 16;
#pragma unroll
    for (int c = 0; c < 8; c++) {
      unsigned lo = wds[c] & 0xFFFFu, hi = wds[c] >> 16;
      lo = (lo & 0x8000u) ? (lo ^ 0xFFFFu) : (lo | 0x8000u);
      hi = (hi & 0x8000u) ? (hi ^ 0xFFFFu) : (hi | 0x8000u);
      key[2 * c]     = (lo << 10) | (unsigned)(base - 2 * c);
      key[2 * c + 1] = (hi << 10) | (unsigned)(base - 2 * c - 1);
    }
  }

  // in-register bitonic sort, descending (all indices static)
#pragma unroll
  for (int k = 2; k <= 16; k <<= 1) {
#pragma unroll
    for (int j = k >> 1; j > 0; j >>= 1) {
#pragma unroll
      for (int i = 0; i < 16; i++) {
        const int l = i ^ j;
        if (l > i) {
          const unsigned a = key[i], b = key[l];
          const unsigned hi = a > b ? a : b, lo = a > b ? b : a;
          const bool desc = ((i & k) == 0);
          key[i] = desc ? hi : lo;
          key[l] = desc ? lo : hi;
        }
      }
    }
  }

  // stash tail in LDS (row stride 64 u32 -> bank = lane%32, conflict-free)
#pragma unroll
  for (int j = 1; j < 16; j++) heads[wv][j][lane] = key[j];
  heads[wv][16][lane] = 0u;   // sentinel: real keys are always > 0

  unsigned h = key[0];
  int ptr = 1;
  unsigned* op = ski + (size_t)gl * KNN;

#pragma unroll 1
  for (int it = 0; it < KNN; it++) {
    const unsigned nxt = heads[wv][ptr][lane];   // dynamic LDS index: fine
    unsigned w = h;
#pragma unroll
    for (int off = 1; off < 64; off <<= 1) {
      const unsigned o = __shfl_xor(w, off);
      w = o > w ? o : w;
    }
    if (lane == 0) op[it] = w;
    const bool me = (h == w);    // keys globally unique -> exactly one lane
    h = me ? nxt : h;
    ptr += me ? 1 : 0;
  }
}

// ---------------------------------------------------------------------------
// K4 v3: staircase candidates (119 of 1024) + bitonic sort of 128 across
// 64 lanes x 2 regs; softmax + value gather from sorted lanes.
// Inputs are packed keys from K3 (decoded here).
// ---------------------------------------------------------------------------
__device__ const short CAND[128] = {
  // i=0: j=0..31
  0,1,2,3,4,5,6,7,8,9,10,11,12,13,14,15,16,17,18,19,20,21,22,23,24,25,26,27,28,29,30,31,
  // i=1: j=0..15
  32,33,34,35,36,37,38,39,40,41,42,43,44,45,46,47,
  // i=2: j=0..9
  64,65,66,67,68,69,70,71,72,73,
  // i=3: j=0..7
  96,97,98,99,100,101,102,103,
  // i=4: j=0..5
  128,129,130,131,132,133,
  // i=5: j=0..4
  160,161,162,163,164,
  // i=6: j=0..3
  192,193,194,195,
  // i=7: j=0..3
  224,225,226,227,
  // i=8,9: j=0..2
  256,257,258, 288,289,290,
  // i=10..15: j=0..1
  320,321, 352,353, 384,385, 416,417, 448,449, 480,481,
  // i=16..31: j=0
  512,544,576,608,640,672,704,736,768,800,832,864,896,928,960,992,
  // pad
  -1,-1,-1,-1,-1,-1,-1,-1,-1
};

__global__ __launch_bounds__(256) void combine_topk2(const unsigned* __restrict__ ski,
                                                     const float* __restrict__ values,
                                                     float* __restrict__ y) {
  const int n = blockIdx.x;
  const int w = threadIdx.x >> 6;   // head
  const int lane = threadIdx.x & 63;

  __shared__ float s1v[4][32], s2v[4][32];
  __shared__ int s1i[4][32], s2i[4][32];
  __shared__ float yh[4][32];

  const size_t g1 = ((size_t)(n * 8 + w * 2)) * KNN;   // (n,h,c=0)
  const size_t g2 = g1 + KNN;                          // (n,h,c=1)
  {
    const unsigned kk = ski[(lane < 32) ? (g1 + lane) : (g2 + lane - 32)];
    const float val = dec_key(kk);
    const int idx = 1023 - (int)(kk & 1023u);
    if (lane < 32) { s1v[w][lane] = val; s1i[w][lane] = idx; }
    else           { s2v[w][lane - 32] = val; s2i[w][lane - 32] = idx; }
  }

  // candidate values: virtual index e = reg*64 + lane
  int id0 = CAND[lane], id1 = CAND[64 + lane];
  float v0 = (id0 < 0) ? -3e38f : s1v[w][id0 >> 5] + s2v[w][id0 & 31];
  float v1 = (id1 < 0) ? -3e38f : s1v[w][id1 >> 5] + s2v[w][id1 & 31];

  // bitonic sort, descending by e. 28 compare-exchange stages.
#pragma unroll
  for (int kb = 1; kb <= 7; ++kb) {
    const int k = 1 << kb;
#pragma unroll
    for (int jb = kb - 1; jb >= 0; --jb) {
      const int j = 1 << jb;
      if (j == 64) {
        // in-thread CE between e=lane and e=64+lane (k=128: descending)
        if (v1 > v0) {
          const float tv = v0; v0 = v1; v1 = tv;
          const int ti = id0; id0 = id1; id1 = ti;
        }
      } else {
        {
          const int e = lane;
          const float ov = __shfl_xor(v0, j);
          const int oi = __shfl_xor(id0, j);
          const bool up = (e & k) != 0;
          const bool low = (e & j) == 0;
          const bool take = (low != up) ? (ov > v0) : (ov < v0);
          v0 = take ? ov : v0;
          id0 = take ? oi : id0;
        }
        {
          const int e = 64 + lane;
          const float ov = __shfl_xor(v1, j);
          const int oi = __shfl_xor(id1, j);
          const bool up = (e & k) != 0;
          const bool low = (e & j) == 0;
          const bool take = (low != up) ? (ov > v1) : (ov < v1);
          v1 = take ? ov : v1;
          id1 = take ? oi : id1;
        }
      }
    }
  }
  // lanes 0..31 of v0/id0 now hold the top-32 descending.

  const float m = __shfl(v0, 0);
  const float ev = __expf(v0 - m);
  float es = ev;
#pragma unroll
  for (int off = 16; off; off >>= 1) es += __shfl_xor(es, off);   // valid on lanes 0..31

  const int c0 = (id0 < 0) ? 0 : id0;
  const int mi = s1i[w][c0 >> 5] * NKEYS + s2i[w][c0 & 31];

  // gather: lane = g*32 + d; combo = 2*it + g
  const int g = lane >> 5, d = lane & 31;
  float acc = 0.f;
#pragma unroll
  for (int it = 0; it < 16; it++) {
    const int combo = 2 * it + g;
    const float wgt = __shfl(ev, combo);
    const int midx = __shfl(mi, combo);
    acc += wgt * values[(size_t)midx * VDIM + d];
  }
  acc += __shfl_xor(acc, 32);
  if (lane < 32) yh[w][d] = acc / es;
  __syncthreads();
  if (w == 0 && lane < 32) {
    y[(size_t)n * VDIM + lane] = yh[0][lane] + yh[1][lane] + yh[2][lane] + yh[3][lane];
  }
}

// ---------------------------------------------------------------------------
// K5: out = x + y @ W_r + b_r.  8 tokens per block; W_r columns reused in regs.
// ---------------------------------------------------------------------------
__global__ __launch_bounds__(256) void out_proj(const float* __restrict__ x,
                                                const float* __restrict__ yv,
                                                const float* __restrict__ Wr,
                                                const float* __restrict__ br,
                                                float* __restrict__ out) {
  const int nb = blockIdx.x * 8;
  const int t = threadIdx.x;
  __shared__ float ys[8][VDIM];
  ys[t >> 5][t & 31] = yv[(size_t)nb * VDIM + t];
  __syncthreads();

#pragma unroll
  for (int rep = 0; rep < 4; rep++) {
    const int d = t + rep * 256;
    float wcol[VDIM];
#pragma unroll
    for (int vv = 0; vv < VDIM; vv++) wcol[vv] = Wr[vv * DDIM + d];
    const float bb = br[d];
#pragma unroll 1
    for (int tok = 0; tok < 8; tok++) {
      float a = bb;
#pragma unroll
      for (int vv = 0; vv < VDIM; vv++) a = fmaf(ys[tok][vv], wcol[vv], a);
      const size_t o = (size_t)(nb + tok) * DDIM + d;
      out[o] = x[o] + a;
    }
  }
}

// ---------------------------------------------------------------------------
extern "C" void kernel_launch(void* const* d_in, const int* in_sizes, int n_in,
                              void* d_out, int out_size, void* d_ws, size_t ws_size,
                              hipStream_t stream) {
  const float* x      = (const float*)d_in[0];
  const float* W_q    = (const float*)d_in[1];
  const float* b_q    = (const float*)d_in[2];
  const float* keys   = (const float*)d_in[3];
  const float* values = (const float*)d_in[4];
  const float* W_r    = (const float*)d_in[5];
  const float* b_r    = (const float*)d_in[6];
  float* out = (float*)d_out;

  // Workspace layout (512 MiB available; ~181 MB used)
  unsigned short* qb    = (unsigned short*)d_ws;        // 8192*1024 bf16
  unsigned short* xb    = qb + (size_t)NTOK * DDIM;     // 8192*1024 bf16
  unsigned short* Wqt   = xb + (size_t)NTOK * DDIM;     // 1024*1024 bf16 (N x K)
  unsigned short* keysb = Wqt + (size_t)DDIM * DDIM;    // 8*1024*128 bf16
  unsigned* ski = (unsigned*)(keysb + (size_t)NHEADS * 2 * NKEYS * HALF);  // 65536*32 u32
  float* y = (float*)(ski + (size_t)NTOK * NHEADS * 2 * KNN);              // 8192*32 f32
  unsigned short* sc = (unsigned short*)(y + (size_t)NTOK * VDIM);         // 8192*8192 bf16 (134MB)

  // Convert inputs to bf16
  cvt_bf16<<<(NTOK * DDIM / 4 + 255) / 256, 256, 0, stream>>>(x, xb, NTOK * DDIM / 4);
  cvt_bf16<<<(NHEADS * 2 * NKEYS * HALF / 4 + 255) / 256, 256, 0, stream>>>(
      keys, keysb, NHEADS * 2 * NKEYS * HALF / 4);
  transpose_cvt<<<dim3(16, 16), 256, 0, stream>>>(W_q, Wqt);

  // K1: q = x @ W_q + b_q -> bf16   (8192x1024, K=1024)
  gemm_mfma<true, true, false><<<dim3(NTOK / 128, DDIM / 128, 1), 256, 0, stream>>>(
      xb, Wqt, b_q, qb, DDIM, DDIM, DDIM, DDIM, 0, 0, 0);

  // K2: all chunks+head-halves in one dispatch; bf16 score output.
  // sc[n][hc][key], row stride 8192 (elements).
  gemm_mfma<true, false, true><<<dim3(CHUNK / 128, NKEYS / 128, (NTOK / CHUNK) * NHEADS * 2),
                                 256, 0, stream>>>(
      qb, keysb, nullptr, sc, HALF, DDIM, HALF, NHEADS * 2 * NKEYS, 0, 0, 0);

  // K3: top-32 per (n,hc) group -> packed keys
  topk_subkeys<<<NTOK * NHEADS * 2 / 4, 256, 0, stream>>>(sc, ski);

  // K4: staircase + bitonic top-32, softmax, value gather, head sum
  combine_topk2<<<NTOK, 256, 0, stream>>>(ski, values, y);

  // K5: out = x + y @ W_r + b_r
  out_proj<<<NTOK / 8, 256, 0, stream>>>(x, y, W_r, b_r, out);
}